// Round 8
// baseline (141.893 us; speedup 1.0000x reference)
//
#include <hip/hip_runtime.h>
#include <cstdint>
#include <cstddef>

// Problem constants
#define NIMG 32
#define C    128
#define OC   128
#define HW   112
#define HWSZ (HW * HW)       // 12544
#define NTAP 9
// channel-last padded activation buffer: xq[n][114][114][128] int8
#define PHW  114
#define XROW (PHW * C)       // 14592 B per padded row
#define XIMG (PHW * XROW)    // 1,663,488 B per image
#define XQ_BYTES ((size_t)NIMG * XIMG)          // 53,231,616
#define AWQ_BYTES ((size_t)4 * 9 * 4 * 64 * 16) // 147,456

typedef int v4i  __attribute__((ext_vector_type(4)));
typedef int v16i __attribute__((ext_vector_type(16)));

// sign byte: +1 (0x01) if x>=0 else -1 (0xFF)
__device__ __forceinline__ uint32_t sign_byte(uint32_t bits) {
    return ((bits >> 31) * 0xFEu) ^ 1u;
}

// ---------------------------------------------------------------------------
// Zero the border cells of xq (rows 0,113 full; cols 0,113 for rows 1..112).
__global__ void fill_border(uint8_t* __restrict__ xq) {
    int tid = blockIdx.x * blockDim.x + threadIdx.x;   // 32*3616 total
    int n = tid / 3616, u = tid % 3616;
    size_t off;
    if (u < 912)        off = (size_t)u * 16;                              // top row
    else if (u < 1824)  off = (size_t)113 * XROW + (size_t)(u - 912) * 16; // bottom
    else {
        int j = u - 1824;                 // 0..1791
        int r = (j >> 4) + 1;             // rows 1..112
        int side = (j >> 3) & 1;          // 0=left col, 1=right col
        int cu = j & 7;
        off = (size_t)r * XROW + (size_t)side * (113 * C) + (size_t)cu * 16;
    }
    *(uint4*)(xq + (size_t)n * XIMG + off) = make_uint4(0u, 0u, 0u, 0u);
}

// ---------------------------------------------------------------------------
// Pack x (N,C,112,112) fp32 -> xq channel-last int8 via LDS transpose.
// Block = (n, pair of rows). Load phase: 224 threads x 32 float4 loads.
__global__ __launch_bounds__(256) void pack_x_cl(const float* __restrict__ x,
                                                 uint8_t* __restrict__ xq) {
    __shared__ __align__(16) uint8_t slds[2 * 112 * 144];   // [row][px][c], pad 144
    int n = blockIdx.x / 56, hp = blockIdx.x % 56;
    int h0 = hp * 2;

    int task = threadIdx.x;
    if (task < 224) {
        int r = task / 112, rem = task % 112;
        int word = rem / 28, pxg = rem % 28;      // consecutive lanes -> consecutive px4
        const float* xp = x + ((size_t)(n * C + word * 32)) * HWSZ
                            + (size_t)(h0 + r) * HW + pxg * 4;
        uint32_t dw[4][8];
        #pragma unroll
        for (int i = 0; i < 8; ++i) {
            uint32_t a0 = 0, a1 = 0, a2 = 0, a3 = 0;
            #pragma unroll
            for (int b = 0; b < 4; ++b) {
                float4 v = *reinterpret_cast<const float4*>(xp + (size_t)(i * 4 + b) * HWSZ);
                a0 |= sign_byte(__float_as_uint(v.x)) << (8 * b);
                a1 |= sign_byte(__float_as_uint(v.y)) << (8 * b);
                a2 |= sign_byte(__float_as_uint(v.z)) << (8 * b);
                a3 |= sign_byte(__float_as_uint(v.w)) << (8 * b);
            }
            dw[0][i] = a0; dw[1][i] = a1; dw[2][i] = a2; dw[3][i] = a3;
        }
        #pragma unroll
        for (int j = 0; j < 4; ++j) {
            uint8_t* sp = &slds[(size_t)((r * 112) + pxg * 4 + j) * 144 + word * 32];
            *(uint4*)sp        = make_uint4(dw[j][0], dw[j][1], dw[j][2], dw[j][3]);
            *(uint4*)(sp + 16) = make_uint4(dw[j][4], dw[j][5], dw[j][6], dw[j][7]);
        }
    }
    __syncthreads();

    uint8_t* dst = xq + (size_t)n * XIMG + (size_t)(h0 + 1) * XROW + C;  // col 1
    #pragma unroll
    for (int rep = 0; rep < 7; ++rep) {
        int u = threadIdx.x + rep * 256;          // < 1792
        int row = u / 896, i = u % 896;           // 896*16B = cols 1..112 of one row
        *(uint4*)(dst + (size_t)row * XROW + (size_t)i * 16) =
            *(const uint4*)&slds[(size_t)(row * 112 + (i >> 3)) * 144 + (i & 7) * 16];
    }
}

// ---------------------------------------------------------------------------
// Build A-fragments for mfma_i32_32x32x32_i8:
// awq[f][lane][16B], f = (wv*9 + tap)*4 + ks; lane l: row m = l&31,
// channel = ks*32 + (l>>5)*16 + byte.  A[m][k] = sign(w[wv*32+m][chan][tap]).
__global__ void pack_w_frag(const float* __restrict__ w, uint32_t* __restrict__ awq) {
    int tid = blockIdx.x * blockDim.x + threadIdx.x;   // 144 frags * 256 dwords
    int d = tid & 3, l = (tid >> 2) & 63, f = tid >> 8;
    int ks = f & 3, tf = f >> 2;
    int tap = tf % 9, wv = tf / 9;
    int o = wv * 32 + (l & 31);
    int cb = ks * 32 + ((l >> 5) & 1) * 16 + d * 4;
    uint32_t acc = 0;
    #pragma unroll
    for (int jj = 0; jj < 4; ++jj) {
        uint32_t bits = __float_as_uint(w[(size_t)(o * C + cb + jj) * NTAP + tap]);
        acc |= sign_byte(bits) << (8 * jj);
    }
    awq[tid] = acc;
}

// ---------------------------------------------------------------------------
// Binary conv as int8 implicit GEMM, 32x32x32 MFMA, 2 output rows per block.
// Block = (n, row-pair), XCD-swizzled (1792 = 8*224 -> 4 contiguous images
// per XCD: adjacent blocks share 2 of 4 staged rows via L2).
// Stage 4 padded rows (58368 B, XOR-swizzled); 4 waves x 32 o; 7 N-tiles of
// 32 px spanning the 2 rows (224 = 7*32 exactly); per tile 36 ds_read_b128 +
// 36 MFMA.  D layout: col=lane&31 (px) -> 2x128B store segments per inst.
__global__ __launch_bounds__(256, 2) void bconv_mfma(const uint8_t* __restrict__ xq,
                                                     const uint8_t* __restrict__ awq,
                                                     float* __restrict__ out) {
    __shared__ __align__(16) uint8_t sxq[4 * XROW];    // 58368 B
    int bid = blockIdx.x;                              // 1792 = 8 * 224, bijective
    int swz = (bid & 7) * 224 + (bid >> 3);
    int n = swz / 56, hp = swz % 56;
    int h0 = hp * 2;

    const uint8_t* src = xq + (size_t)n * XIMG + (size_t)h0 * XROW;
    #pragma unroll
    for (int rep = 0; rep < 15; ++rep) {
        int u = threadIdx.x + rep * 256;
        if (u < 3648) {
            int pix = (u >> 3) % PHW;                  // col within padded row
            uint4 v = *(const uint4*)(src + (size_t)u * 16);
            int a = (u * 16) ^ ((pix & 7) << 4);       // swizzle within 128B cell
            *(uint4*)&sxq[a] = v;
        }
    }

    int wv = threadIdx.x >> 6, l = threadIdx.x & 63;
    int l31 = l & 31, lk = (l >> 5) * 16;              // k-group byte offset

    // resident A fragments: 9 taps x 4 k-slices (144 VGPR)
    v4i A[9][4];
    #pragma unroll
    for (int tap = 0; tap < 9; ++tap)
        #pragma unroll
        for (int ks = 0; ks < 4; ++ks) {
            int f = (wv * 9 + tap) * 4 + ks;
            A[tap][ks] = *(const v4i*)(awq + (size_t)f * 1024 + (size_t)l * 16);
        }
    __syncthreads();

    float* outb = out + ((size_t)n * OC + wv * 32) * HWSZ + (size_t)h0 * HW;

    for (int nt = 0; nt < 7; ++nt) {
        int p = nt * 32 + l31;                         // px within the 2-row strip
        int rl = (p >= HW) ? 1 : 0;
        int w = p - rl * HW;

        int ad[3][4];
        #pragma unroll
        for (int kw = 0; kw < 3; ++kw) {
            int col = w + kw;                          // padded col, in-bounds
            int x4 = (col & 7) << 4;
            int b0 = rl * XROW + col * C;
            #pragma unroll
            for (int ks = 0; ks < 4; ++ks)
                ad[kw][ks] = b0 + ((ks * 32 + lk) ^ x4);
        }

        v16i acc = {0,0,0,0,0,0,0,0,0,0,0,0,0,0,0,0};
        #pragma unroll
        for (int kh = 0; kh < 3; ++kh)
            #pragma unroll
            for (int kw = 0; kw < 3; ++kw)
                #pragma unroll
                for (int ks = 0; ks < 4; ++ks) {
                    v4i b = *(const v4i*)&sxq[kh * XROW + ad[kw][ks]];
                    acc = __builtin_amdgcn_mfma_i32_32x32x32_i8(
                              A[kh * 3 + kw][ks], b, acc, 0, 0, 0);
                }

        #pragma unroll
        for (int r = 0; r < 16; ++r) {
            int oof = (r & 3) + 8 * (r >> 2) + 4 * (l >> 5);   // D row (o)
            outb[(size_t)oof * HWSZ + rl * HW + w] = (float)acc[r];
        }
    }
}

// ===========================================================================
extern "C" void kernel_launch(void* const* d_in, const int* in_sizes, int n_in,
                              void* d_out, int out_size, void* d_ws, size_t ws_size,
                              hipStream_t stream) {
    const float* x   = (const float*)d_in[0];
    const float* wts = (const float*)d_in[1];
    float* out = (float*)d_out;
    uint8_t* ws = (uint8_t*)d_ws;

    uint8_t*  xq  = ws;
    uint32_t* awq = (uint32_t*)(ws + XQ_BYTES);

    hipLaunchKernelGGL(fill_border, dim3(NIMG * 3616 / 256), dim3(256), 0, stream, xq);
    hipLaunchKernelGGL(pack_w_frag, dim3(144), dim3(256), 0, stream, wts, awq);
    hipLaunchKernelGGL(pack_x_cl, dim3(NIMG * 56), dim3(256), 0, stream, x, xq);
    hipLaunchKernelGGL(bconv_mfma, dim3(NIMG * 56), dim3(256), 0, stream,
                       xq, (const uint8_t*)awq, out);
}

// Round 9
// 126.587 us; speedup vs baseline: 1.1209x; 1.1209x over previous
//
#include <hip/hip_runtime.h>
#include <cstdint>
#include <cstddef>

// Problem constants
#define NIMG 32
#define C    128
#define OC   128
#define HW   112
#define HWSZ (HW * HW)       // 12544
#define NTAP 9
#define PHW  114             // padded spatial dim
#define XROW (PHW * C)       // 14592 B per padded LDS row
#define AWQ_BYTES ((size_t)4 * 9 * 4 * 64 * 16) // 147,456

typedef int v4i  __attribute__((ext_vector_type(4)));
typedef int v16i __attribute__((ext_vector_type(16)));

// ---------------------------------------------------------------------------
// Build A-fragments for mfma_i32_32x32x32_i8:
// awq[f][lane][16B], f = (wv*9 + tap)*4 + ks; lane l: row m = l&31,
// channel = ks*32 + (l>>5)*16 + byte.  A[m][k] = sign(w[wv*32+m][chan][tap]).
__global__ void pack_w_frag(const float* __restrict__ w, uint32_t* __restrict__ awq) {
    int tid = blockIdx.x * blockDim.x + threadIdx.x;   // 144 frags * 256 dwords
    int d = tid & 3, l = (tid >> 2) & 63, f = tid >> 8;
    int ks = f & 3, tf = f >> 2;
    int tap = tf % 9, wv = tf / 9;
    int o = wv * 32 + (l & 31);
    int cb = ks * 32 + ((l >> 5) & 1) * 16 + d * 4;
    uint32_t acc = 0;
    #pragma unroll
    for (int jj = 0; jj < 4; ++jj) {
        uint32_t bits = __float_as_uint(w[(size_t)(o * C + cb + jj) * NTAP + tap]);
        acc |= (((bits >> 31) * 0xFEu) ^ 1u) << (8 * jj);
    }
    awq[tid] = acc;
}

// ---------------------------------------------------------------------------
// Fused binary conv: stage 4 fp32 image rows directly from x, sign-pack to
// int8 channel-last in registers, swizzled ds_write (borders zero-filled in
// LDS); then int8 implicit GEMM exactly as R8 (32x32x32 MFMA, 2 output rows
// per block, XCD-swizzled blocks so adjacent row-pairs share x rows via L2).
__global__ __launch_bounds__(256, 2) void bconv_fused(const float* __restrict__ x,
                                                      const uint8_t* __restrict__ awq,
                                                      float* __restrict__ out) {
    __shared__ __align__(16) uint8_t sxq[4 * XROW];    // 58368 B: rows h0-1..h0+2
    int bid = blockIdx.x;                              // 1792 = 8 * 224, bijective
    int swz = (bid & 7) * 224 + (bid >> 3);
    int n = swz / 56, hp = swz % 56;
    int h0 = hp * 2;

    // ---- phase 1: load + sign-pack + swizzled LDS stage --------------------
    #pragma unroll
    for (int rep = 0; rep < 2; ++rep) {
        int task = threadIdx.x + rep * 256;
        if (task < 448) {
            int r = task / 112;                        // staged row 0..3
            int rem = task % 112;
            int word = rem / 28, pxg = rem % 28;       // 32-chan group, 4-px group
            int hr = h0 - 1 + r;                       // image row
            int col0 = 1 + pxg * 4;                    // padded col of first px
            int sbase = r * XROW;
            if (hr >= 0 && hr < HW) {
                const float* xp = x + ((size_t)(n * C + word * 32)) * HWSZ
                                    + (size_t)hr * HW + pxg * 4;
                uint32_t dw[4][8];
                #pragma unroll
                for (int j = 0; j < 4; ++j)
                    #pragma unroll
                    for (int d = 0; d < 8; ++d) dw[j][d] = 0u;
                #pragma unroll
                for (int c = 0; c < 32; ++c) {
                    float4 v = *reinterpret_cast<const float4*>(xp + (size_t)c * HWSZ);
                    uint32_t bm = 0xFFu << (8 * (c & 3));
                    int d = c >> 2;
                    dw[0][d] |= ((uint32_t)((int)__float_as_uint(v.x) >> 31)) & bm;
                    dw[1][d] |= ((uint32_t)((int)__float_as_uint(v.y) >> 31)) & bm;
                    dw[2][d] |= ((uint32_t)((int)__float_as_uint(v.z) >> 31)) & bm;
                    dw[3][d] |= ((uint32_t)((int)__float_as_uint(v.w) >> 31)) & bm;
                }
                #pragma unroll
                for (int j = 0; j < 4; ++j) {
                    int col = col0 + j;
                    int cb = col * 128 + word * 32;
                    int sw = (col & 7) << 4;
                    uint32_t d0 = (dw[j][0] & 0xFEFEFEFEu) ^ 0x01010101u;
                    uint32_t d1 = (dw[j][1] & 0xFEFEFEFEu) ^ 0x01010101u;
                    uint32_t d2 = (dw[j][2] & 0xFEFEFEFEu) ^ 0x01010101u;
                    uint32_t d3 = (dw[j][3] & 0xFEFEFEFEu) ^ 0x01010101u;
                    *(uint4*)&sxq[sbase + (cb ^ sw)] = make_uint4(d0, d1, d2, d3);
                    uint32_t d4 = (dw[j][4] & 0xFEFEFEFEu) ^ 0x01010101u;
                    uint32_t d5 = (dw[j][5] & 0xFEFEFEFEu) ^ 0x01010101u;
                    uint32_t d6 = (dw[j][6] & 0xFEFEFEFEu) ^ 0x01010101u;
                    uint32_t d7 = (dw[j][7] & 0xFEFEFEFEu) ^ 0x01010101u;
                    *(uint4*)&sxq[sbase + ((cb + 16) ^ sw)] = make_uint4(d4, d5, d6, d7);
                }
            } else {
                // image row out of range: zero-fill this task's LDS span
                #pragma unroll
                for (int j = 0; j < 4; ++j) {
                    int col = col0 + j;
                    int cb = col * 128 + word * 32;
                    int sw = (col & 7) << 4;
                    *(uint4*)&sxq[sbase + (cb ^ sw)]        = make_uint4(0u, 0u, 0u, 0u);
                    *(uint4*)&sxq[sbase + ((cb + 16) ^ sw)] = make_uint4(0u, 0u, 0u, 0u);
                }
            }
        } else if (task < 456) {
            // pad columns 0 and 113 of each staged row
            int j = task - 448;
            int r = j >> 1, side = j & 1;
            int col = side ? 113 : 0;
            int sw = (col & 7) << 4;
            #pragma unroll
            for (int k = 0; k < 8; ++k)
                *(uint4*)&sxq[r * XROW + ((col * 128 + k * 16) ^ sw)] =
                    make_uint4(0u, 0u, 0u, 0u);
        }
    }

    // resident A fragments: 9 taps x 4 k-slices (144 VGPR)
    int wv = threadIdx.x >> 6, l = threadIdx.x & 63;
    int l31 = l & 31, lk = (l >> 5) * 16;
    v4i A[9][4];
    #pragma unroll
    for (int tap = 0; tap < 9; ++tap)
        #pragma unroll
        for (int ks = 0; ks < 4; ++ks) {
            int f = (wv * 9 + tap) * 4 + ks;
            A[tap][ks] = *(const v4i*)(awq + (size_t)f * 1024 + (size_t)l * 16);
        }
    __syncthreads();

    // ---- phase 2: 32x32x32 int8 MFMA over 7 N-tiles of 32 px ---------------
    float* outb = out + ((size_t)n * OC + wv * 32) * HWSZ + (size_t)h0 * HW;

    for (int nt = 0; nt < 7; ++nt) {
        int p = nt * 32 + l31;                         // px within the 2-row strip
        int rl = (p >= HW) ? 1 : 0;
        int w = p - rl * HW;

        int ad[3][4];
        #pragma unroll
        for (int kw = 0; kw < 3; ++kw) {
            int col = w + kw;                          // padded col, in-bounds
            int x4 = (col & 7) << 4;
            int b0 = rl * XROW + col * C;
            #pragma unroll
            for (int ks = 0; ks < 4; ++ks)
                ad[kw][ks] = b0 + ((ks * 32 + lk) ^ x4);
        }

        v16i acc = {0,0,0,0,0,0,0,0,0,0,0,0,0,0,0,0};
        #pragma unroll
        for (int kh = 0; kh < 3; ++kh)
            #pragma unroll
            for (int kw = 0; kw < 3; ++kw)
                #pragma unroll
                for (int ks = 0; ks < 4; ++ks) {
                    v4i b = *(const v4i*)&sxq[kh * XROW + ad[kw][ks]];
                    acc = __builtin_amdgcn_mfma_i32_32x32x32_i8(
                              A[kh * 3 + kw][ks], b, acc, 0, 0, 0);
                }

        #pragma unroll
        for (int r = 0; r < 16; ++r) {
            int oof = (r & 3) + 8 * (r >> 2) + 4 * (l >> 5);   // D row (o)
            outb[(size_t)oof * HWSZ + rl * HW + w] = (float)acc[r];
        }
    }
}

// ===========================================================================
extern "C" void kernel_launch(void* const* d_in, const int* in_sizes, int n_in,
                              void* d_out, int out_size, void* d_ws, size_t ws_size,
                              hipStream_t stream) {
    const float* x   = (const float*)d_in[0];
    const float* wts = (const float*)d_in[1];
    float* out = (float*)d_out;
    uint32_t* awq = (uint32_t*)d_ws;

    hipLaunchKernelGGL(pack_w_frag, dim3(144), dim3(256), 0, stream, wts, awq);
    hipLaunchKernelGGL(bconv_fused, dim3(NIMG * 56), dim3(256), 0, stream,
                       x, (const uint8_t*)awq, out);
}